// Round 5
// baseline (560.612 us; speedup 1.0000x reference)
//
#include <hip/hip_runtime.h>

// GIN (2x GINE conv): bucketed CSR build + fused gather+MFMA-GEMM kernels.
// Pipeline:  A(bf16)  = x @ W11 + b11                                (gemm_mfma)
//            fused2:   gather(A) -> LDS tile -> @W12+cnt*b12,relu -> LDS
//                      -> @W21+b21 -> A2(bf16)
//            fused1:   gather(A2) -> LDS tile -> @W22+cnt*b22 -> out(fp32)
// CSR build: bin edges into 2048-node buckets (LDS tile sort, coalesced chunk
// appends), then per-bucket exact counting sort confined to one CU's L2.

typedef unsigned int uint;
typedef __attribute__((ext_vector_type(8))) short bf16x8;
typedef __attribute__((ext_vector_type(4))) float f32x4;

#define BSHIFT 11            // 2048 nodes per bucket
#define BNODES (1 << BSHIFT)

static __device__ __forceinline__ unsigned short f2bf(float f) {
    uint u = __float_as_uint(f);
    uint r = (u + 0x7fffu + ((u >> 16) & 1u)) >> 16;
    return (unsigned short)r;
}

// ---------------- init ----------------

__global__ void init_kernel(int* bcnt, int* ptr, int N, int E) {
    int i = threadIdx.x;
    if (i < 64) bcnt[i] = 0;
    if (i == 0) ptr[N] = E;
}

// ---------------- weight prep: W[K][128] fp32 -> Wt[128][K] bf16 ----------------

__global__ void wprep_all(const float* __restrict__ W11, const float* __restrict__ W12,
                          const float* __restrict__ W21, const float* __restrict__ W22,
                          unsigned short* Wt11, unsigned short* Wt12,
                          unsigned short* Wt21, unsigned short* Wt22) {
    int idx = blockIdx.x * 256 + threadIdx.x;
    const float* W; unsigned short* Wt; int K; int off;
    if (idx < 64 * 128)        { W = W11; Wt = Wt11; K = 64;  off = idx; }
    else if (idx < 192 * 128)  { W = W12; Wt = Wt12; K = 128; off = idx - 64 * 128; }
    else if (idx < 320 * 128)  { W = W21; Wt = Wt21; K = 128; off = idx - 192 * 128; }
    else if (idx < 448 * 128)  { W = W22; Wt = Wt22; K = 128; off = idx - 320 * 128; }
    else return;
    int k = off >> 7, n = off & 127;
    Wt[n * K + k] = f2bf(W[k * 128 + n]);
}

// ---------------- binning: tile-sort in LDS, coalesced chunk appends ----------------

__global__ __launch_bounds__(256) void bin_kernel(
    const int* __restrict__ src, const int* __restrict__ dst,
    const float* __restrict__ ea, int* __restrict__ bcnt,
    int2* __restrict__ barr, int CAP, int E, int B) {
    __shared__ int hist[64];
    __shared__ int bbase[64];
    __shared__ int gbase[64];
    __shared__ int2 sorted[2048];
    __shared__ unsigned char bof[2048];
    const int tileBase = blockIdx.x * 2048;
    int n = E - tileBase; if (n > 2048) n = 2048; if (n <= 0) return;
    const int tid = threadIdx.x;
    if (tid < 64) hist[tid] = 0;
    __syncthreads();

    int2 ent[8]; int bk[8]; int rk[8];
#pragma unroll
    for (int k = 0; k < 8; k++) {
        int i = k * 256 + tid;
        bk[k] = -1;
        if (i < n) {
            int e = tileBase + i;
            int s = src[e], d = dst[e];
            float2 a = reinterpret_cast<const float2*>(ea)[e];
            int b = d >> BSHIFT;
            int dloc = d & (BNODES - 1);
            ent[k].x = s | (dloc << 17);
            ent[k].y = (int)((uint)f2bf(a.x) | ((uint)f2bf(a.y) << 16));
            bk[k] = b;
            rk[k] = atomicAdd(&hist[b], 1);
        }
    }
    __syncthreads();
    if (tid == 0) {
        int run = 0;
        for (int b = 0; b < B; b++) { bbase[b] = run; run += hist[b]; }
    }
    __syncthreads();
    if (tid < B && hist[tid] > 0) gbase[tid] = atomicAdd(&bcnt[tid], hist[tid]);
    __syncthreads();
#pragma unroll
    for (int k = 0; k < 8; k++) {
        if (bk[k] >= 0) {
            int p = bbase[bk[k]] + rk[k];
            sorted[p] = ent[k];
            bof[p] = (unsigned char)bk[k];
        }
    }
    __syncthreads();
    for (int i = tid; i < n; i += 256) {
        int b = bof[i];
        barr[(long)b * CAP + gbase[b] + (i - bbase[b])] = sorted[i];
    }
}

// ---------------- per-bucket exact CSR (one block per bucket) ----------------

__global__ __launch_bounds__(1024) void bucket_csr(
    const int2* __restrict__ barr, const int* __restrict__ bcnt,
    int CAP, int N, int B,
    int2* __restrict__ csr, int* __restrict__ ptr) {
    __shared__ int hist[BNODES];
    __shared__ int pairs[1024];
    __shared__ int lptr[BNODES];
    const int g = blockIdx.x;
    const int tid = threadIdx.x;
    const int cnt = bcnt[g];
    int base = 0;
    for (int b = 0; b < g; b++) base += bcnt[b];

    hist[tid] = 0; hist[tid + 1024] = 0;
    __syncthreads();
    const int2* my = barr + (long)g * CAP;
    for (int i = tid; i < cnt; i += 1024) {
        int dloc = ((uint)my[i].x) >> 17;
        atomicAdd(&hist[dloc], 1);
    }
    __syncthreads();
    int ps = hist[2 * tid] + hist[2 * tid + 1];
    pairs[tid] = ps;
    __syncthreads();
    for (int off = 1; off < 1024; off <<= 1) {
        int t = (tid >= off) ? pairs[tid - off] : 0;
        __syncthreads();
        pairs[tid] += t;
        __syncthreads();
    }
    int excl = pairs[tid] - ps;
    lptr[2 * tid] = excl;
    lptr[2 * tid + 1] = excl + hist[2 * tid];
    __syncthreads();
    for (int i = tid; i < BNODES; i += 1024) {
        long gnode = (long)g * BNODES + i;
        if (gnode <= (long)N) ptr[gnode] = base + lptr[i];
    }
    __syncthreads();
    for (int i = tid; i < cnt; i += 1024) {
        int2 v = my[i];
        int dloc = ((uint)v.x) >> 17;
        int pos = base + atomicAdd(&lptr[dloc], 1);
        int2 o; o.x = v.x & 0x1FFFF; o.y = v.y;
        csr[pos] = o;
    }
}

// ---------------- MFMA GEMM (layer1 first GEMM only: x fp32 -> A bf16) ----------------

template <int K>
__global__ __launch_bounds__(256) void gemm_mfma(
    const float* __restrict__ Ain, const unsigned short* __restrict__ Wt,
    const float* __restrict__ bias, unsigned short* __restrict__ Cout, int N) {
    constexpr int KS = K / 32;
    const int wave = threadIdx.x >> 6;
    const int lane = threadIdx.x & 63;
    const int m = lane & 15, quad = lane >> 4;
    const long rowBase = (long)blockIdx.x * 64;

    bf16x8 bfrag[2][KS];
#pragma unroll
    for (int ct = 0; ct < 2; ct++) {
        int col = (wave * 2 + ct) * 16 + m;
#pragma unroll
        for (int ks = 0; ks < KS; ks++)
            bfrag[ct][ks] = *(const bf16x8*)(Wt + (long)col * K + ks * 32 + quad * 8);
    }

#pragma unroll
    for (int rt = 0; rt < 4; rt++) {
        long row = rowBase + rt * 16 + m;
        long rc = row < N ? row : (long)N - 1;
        bf16x8 afrag[KS];
        const float* arow = Ain + rc * K;
#pragma unroll
        for (int ks = 0; ks < KS; ks++) {
            float4 lo = *(const float4*)(arow + ks * 32 + quad * 8);
            float4 hi = *(const float4*)(arow + ks * 32 + quad * 8 + 4);
            bf16x8 f;
            f[0] = (short)f2bf(lo.x); f[1] = (short)f2bf(lo.y);
            f[2] = (short)f2bf(lo.z); f[3] = (short)f2bf(lo.w);
            f[4] = (short)f2bf(hi.x); f[5] = (short)f2bf(hi.y);
            f[6] = (short)f2bf(hi.z); f[7] = (short)f2bf(hi.w);
            afrag[ks] = f;
        }

#pragma unroll
        for (int ct = 0; ct < 2; ct++) {
            f32x4 acc = {0.f, 0.f, 0.f, 0.f};
#pragma unroll
            for (int ks = 0; ks < KS; ks++)
                acc = __builtin_amdgcn_mfma_f32_16x16x32_bf16(afrag[ks], bfrag[ct][ks], acc, 0, 0, 0);
            int col = (wave * 2 + ct) * 16 + m;
            float b = bias[col];
#pragma unroll
            for (int r = 0; r < 4; r++) {
                long orow = rowBase + rt * 16 + quad * 4 + r;
                if (orow < N) Cout[orow * 128 + col] = f2bf(acc[r] + b);
            }
        }
    }
}

// ---------------- fused gather + GEMM(s) ----------------
// Block = 256 thr = 4 waves, node tile = 64 rows.
// Phase 1: wave w gathers nodes [w*16, w*16+16) into LDS tile (bf16, row
//          stride 272 B -> conflict-free ds_read_b128 fragments).
// Phase 2: tile @ WtA (+ cnt*biasA). TWO: relu -> tile(bf16); else fp32 out.
// Phase 3 (TWO): tile @ WtB + biasB -> bf16 out.

template <bool TWO>
__global__ __launch_bounds__(256) void fused_gather_gemm(
    const uint* __restrict__ Au, const int* __restrict__ ptr,
    const int2* __restrict__ csr, const float* __restrict__ we,
    const unsigned short* __restrict__ WtA, const float* __restrict__ biasA,
    const unsigned short* __restrict__ WtB, const float* __restrict__ biasB,
    void* __restrict__ Cout, int N) {
    __shared__ uint tile[64][68];
    const int wave = threadIdx.x >> 6;
    const int lane = threadIdx.x & 63;
    const int rowBase = blockIdx.x * 64;

    // ---- phase 1: gather ----
    {
        const int t = lane;
        const int c = 2 * t;
        const float w0x = we[c], w0y = we[c + 1];
        const float w1x = we[128 + c], w1y = we[128 + c + 1];
        const char* Ab = (const char*)Au;
        const uint t4 = (uint)t * 4u;
#define LD(sidx) (*(const uint*)(Ab + ((((uint)(sidx)) << 8) + t4)))
#define ACC(rv, ev)                                                      \
        {                                                                \
            float a0 = __uint_as_float(((uint)(ev)) << 16);              \
            float a1 = __uint_as_float(((uint)(ev)) & 0xffff0000u);      \
            float vx = __uint_as_float((rv) << 16);                      \
            float vy = __uint_as_float((rv) & 0xffff0000u);              \
            vx = fmaf(a0, w0x, fmaf(a1, w1x, vx));                       \
            vy = fmaf(a0, w0y, fmaf(a1, w1y, vy));                       \
            ax += fmaxf(vx, 0.f);                                        \
            ay += fmaxf(vy, 0.f);                                        \
        }
        for (int i = 0; i < 16; i++) {
            const int lrow = wave * 16 + i;
            const int node = rowBase + lrow;
            if (node >= N) { tile[lrow][t] = 0; continue; }
            uint selfv = LD(node);
            float ax = fmaxf(__uint_as_float(selfv << 16) + w0x + w1x, 0.f);
            float ay = fmaxf(__uint_as_float(selfv & 0xffff0000u) + w0y + w1y, 0.f);
            int k = ptr[node], end = ptr[node + 1];
            for (; k + 4 <= end; k += 4) {
                int2 c0 = csr[k], c1 = csr[k + 1], c2 = csr[k + 2], c3 = csr[k + 3];
                uint r0 = LD(c0.x); uint r1 = LD(c1.x);
                uint r2 = LD(c2.x); uint r3 = LD(c3.x);
                ACC(r0, c0.y) ACC(r1, c1.y) ACC(r2, c2.y) ACC(r3, c3.y)
            }
            for (; k < end; k++) {
                int2 c0 = csr[k];
                uint r0 = LD(c0.x);
                ACC(r0, c0.y)
            }
            tile[lrow][t] = (uint)f2bf(ax) | ((uint)f2bf(ay) << 16);
        }
#undef ACC
#undef LD
    }
    __syncthreads();

    const int m = lane & 15, quad = lane >> 4;

    // ---- phase 2: tile @ WtA ----
    bf16x8 bfrag[2][4];
#pragma unroll
    for (int ct = 0; ct < 2; ct++) {
        int col = (wave * 2 + ct) * 16 + m;
#pragma unroll
        for (int ks = 0; ks < 4; ks++)
            bfrag[ct][ks] = *(const bf16x8*)(WtA + (long)col * 128 + ks * 32 + quad * 8);
    }
    f32x4 acc[4][2];
#pragma unroll
    for (int rt = 0; rt < 4; rt++) {
        bf16x8 af[4];
        const unsigned short* lr = (const unsigned short*)&tile[rt * 16 + m][0];
#pragma unroll
        for (int ks = 0; ks < 4; ks++)
            af[ks] = *(const bf16x8*)(lr + ks * 32 + quad * 8);
#pragma unroll
        for (int ct = 0; ct < 2; ct++) {
            f32x4 a = {0.f, 0.f, 0.f, 0.f};
#pragma unroll
            for (int ks = 0; ks < 4; ks++)
                a = __builtin_amdgcn_mfma_f32_16x16x32_bf16(af[ks], bfrag[ct][ks], a, 0, 0, 0);
            acc[rt][ct] = a;
        }
    }

    if (TWO) {
        __syncthreads();  // all fragment reads done before overwrite
        unsigned short* ts = (unsigned short*)&tile[0][0];
#pragma unroll
        for (int rt = 0; rt < 4; rt++) {
            float cntf[4];
#pragma unroll
            for (int r = 0; r < 4; r++) {
                int grow = rowBase + rt * 16 + quad * 4 + r;
                cntf[r] = (grow < N) ? (float)(ptr[grow + 1] - ptr[grow] + 1) : 1.f;
            }
#pragma unroll
            for (int ct = 0; ct < 2; ct++) {
                int col = (wave * 2 + ct) * 16 + m;
                float b = biasA[col];
#pragma unroll
                for (int r = 0; r < 4; r++) {
                    int row = rt * 16 + quad * 4 + r;
                    float v = fmaxf(acc[rt][ct][r] + b * cntf[r], 0.f);
                    ts[row * 136 + col] = f2bf(v);
                }
            }
        }
        __syncthreads();

        // ---- phase 3: tile @ WtB + biasB -> bf16 out ----
#pragma unroll
        for (int ct = 0; ct < 2; ct++) {
            int col = (wave * 2 + ct) * 16 + m;
#pragma unroll
            for (int ks = 0; ks < 4; ks++)
                bfrag[ct][ks] = *(const bf16x8*)(WtB + (long)col * 128 + ks * 32 + quad * 8);
        }
        unsigned short* Cb = (unsigned short*)Cout;
#pragma unroll
        for (int rt = 0; rt < 4; rt++) {
            bf16x8 af[4];
            const unsigned short* lr = (const unsigned short*)&tile[rt * 16 + m][0];
#pragma unroll
            for (int ks = 0; ks < 4; ks++)
                af[ks] = *(const bf16x8*)(lr + ks * 32 + quad * 8);
#pragma unroll
            for (int ct = 0; ct < 2; ct++) {
                f32x4 a = {0.f, 0.f, 0.f, 0.f};
#pragma unroll
                for (int ks = 0; ks < 4; ks++)
                    a = __builtin_amdgcn_mfma_f32_16x16x32_bf16(af[ks], bfrag[ct][ks], a, 0, 0, 0);
                int col = (wave * 2 + ct) * 16 + m;
                float b = biasB[col];
#pragma unroll
                for (int r = 0; r < 4; r++) {
                    long grow = rowBase + rt * 16 + quad * 4 + r;
                    if (grow < N) Cb[grow * 128 + col] = f2bf(a[r] + b);
                }
            }
        }
    } else {
        float* Cf = (float*)Cout;
#pragma unroll
        for (int rt = 0; rt < 4; rt++) {
            float cntf[4];
#pragma unroll
            for (int r = 0; r < 4; r++) {
                int grow = rowBase + rt * 16 + quad * 4 + r;
                cntf[r] = (grow < N) ? (float)(ptr[grow + 1] - ptr[grow] + 1) : 1.f;
            }
#pragma unroll
            for (int ct = 0; ct < 2; ct++) {
                int col = (wave * 2 + ct) * 16 + m;
                float b = biasA[col];
#pragma unroll
                for (int r = 0; r < 4; r++) {
                    long grow = rowBase + rt * 16 + quad * 4 + r;
                    if (grow < N) Cf[grow * 128 + col] = acc[rt][ct][r] + b * cntf[r];
                }
            }
        }
    }
}

// ---------------- launch ----------------

extern "C" void kernel_launch(void* const* d_in, const int* in_sizes, int n_in,
                              void* d_out, int out_size, void* d_ws, size_t ws_size,
                              hipStream_t stream) {
    const float* x   = (const float*)d_in[0];
    const int*   ei  = (const int*)d_in[1];
    const float* ea  = (const float*)d_in[2];
    const float* W11 = (const float*)d_in[3];
    const float* b11 = (const float*)d_in[4];
    const float* W12 = (const float*)d_in[5];
    const float* b12 = (const float*)d_in[6];
    const float* W21 = (const float*)d_in[7];
    const float* b21 = (const float*)d_in[8];
    const float* W22 = (const float*)d_in[9];
    const float* b22 = (const float*)d_in[10];
    float* out = (float*)d_out;

    const int N = in_sizes[0] / 64;
    const int E = in_sizes[1] / 2;
    const int* src = ei;
    const int* dst = ei + E;

    const int B = (N + BNODES - 1) >> BSHIFT;
    const int CAP = E / B + 4096;

    // workspace layout; bucket storage aliases the B feature buffer
    char* p = (char*)d_ws;
    unsigned short* A_bf = (unsigned short*)p;  p += (size_t)N * 128 * 2;  // 25.6 MB
    unsigned short* B_bf = (unsigned short*)p;
    int2* barr = (int2*)B_bf;                   p += (size_t)N * 128 * 2;  // 25.6 MB (aliased)
    int2* csr  = (int2*)p;                      p += (size_t)E * 8;        // 12.8 MB
    int* ptr   = (int*)p;                       p += (size_t)(N + 1) * 4;
    int* bcnt  = (int*)p;                       p += 64 * 4;
    unsigned short* Wt11 = (unsigned short*)p;  p += (size_t)64 * 128 * 2;
    unsigned short* Wt12 = (unsigned short*)p;  p += (size_t)128 * 128 * 2;
    unsigned short* Wt21 = (unsigned short*)p;  p += (size_t)128 * 128 * 2;
    unsigned short* Wt22 = (unsigned short*)p;

    const int binBlocks = (E + 2047) / 2048;
    const int tileBlocks = (N + 63) / 64;

    init_kernel<<<1, 64, 0, stream>>>(bcnt, ptr, N, E);
    wprep_all<<<(448 * 128 + 255) / 256, 256, 0, stream>>>(W11, W12, W21, W22,
                                                           Wt11, Wt12, Wt21, Wt22);

    bin_kernel<<<binBlocks, 256, 0, stream>>>(src, dst, ea, bcnt, barr, CAP, E, B);
    bucket_csr<<<B, 1024, 0, stream>>>(barr, bcnt, CAP, N, B, csr, ptr);

    // layer 1 first GEMM: x @ W11 -> A (bf16)
    gemm_mfma<64><<<tileBlocks, 256, 0, stream>>>(x, Wt11, b11, A_bf, N);

    // fused: gather(A) -> @W12(relu,cnt) -> @W21 -> B_bf (= layer2 input)
    fused_gather_gemm<true><<<tileBlocks, 256, 0, stream>>>(
        (const uint*)A_bf, ptr, csr, W11 + 64 * 128,
        Wt12, b12, Wt21, b21, B_bf, N);

    // fused: gather(B_bf) -> @W22(cnt) -> out (fp32)
    fused_gather_gemm<false><<<tileBlocks, 256, 0, stream>>>(
        (const uint*)B_bf, ptr, csr, W21 + 128 * 128,
        Wt22, b22, nullptr, nullptr, out, N);
}

// Round 6
// 401.289 us; speedup vs baseline: 1.3970x; 1.3970x over previous
//
#include <hip/hip_runtime.h>

// GIN (2x GINE conv): bucketed CSR build + standalone CSR gather (max occupancy)
// + bf16 MFMA GEMMs with the two middle GEMMs fused (LDS intermediate).
// Pipeline:  A  = x @ W11 + b11                       (gemm_mfma, f32->bf16)
//            B  = gather(A)                           (gather_kernel)
//            A2 = relu(B@W12 + cnt*b12) @ W21 + b21   (fused_mid, bf16)
//            B2 = gather(A2)                          (gather_kernel)
//            out= B2 @ W22 + cnt*b22                  (gemm_mfma, f32 out)

typedef unsigned int uint;
typedef __attribute__((ext_vector_type(8))) short bf16x8;
typedef __attribute__((ext_vector_type(4))) float f32x4;

#define BSHIFT 11
#define BNODES (1 << BSHIFT)

static __device__ __forceinline__ unsigned short f2bf(float f) {
    uint u = __float_as_uint(f);
    uint r = (u + 0x7fffu + ((u >> 16) & 1u)) >> 16;
    return (unsigned short)r;
}

// ---------------- init ----------------

__global__ void init_kernel(int* bcnt, int* ptr, int N, int E) {
    int i = threadIdx.x;
    if (i < 64) bcnt[i] = 0;
    if (i == 0) ptr[N] = E;
}

// ---------------- weight prep: W[K][128] fp32 -> Wt[128][K] bf16 ----------------

__global__ void wprep_all(const float* __restrict__ W11, const float* __restrict__ W12,
                          const float* __restrict__ W21, const float* __restrict__ W22,
                          unsigned short* Wt11, unsigned short* Wt12,
                          unsigned short* Wt21, unsigned short* Wt22) {
    int idx = blockIdx.x * 256 + threadIdx.x;
    const float* W; unsigned short* Wt; int K; int off;
    if (idx < 64 * 128)        { W = W11; Wt = Wt11; K = 64;  off = idx; }
    else if (idx < 192 * 128)  { W = W12; Wt = Wt12; K = 128; off = idx - 64 * 128; }
    else if (idx < 320 * 128)  { W = W21; Wt = Wt21; K = 128; off = idx - 192 * 128; }
    else if (idx < 448 * 128)  { W = W22; Wt = Wt22; K = 128; off = idx - 320 * 128; }
    else return;
    int k = off >> 7, n = off & 127;
    Wt[n * K + k] = f2bf(W[k * 128 + n]);
}

// ---------------- binning: tile-sort in LDS, coalesced chunk appends ----------------

__global__ __launch_bounds__(256) void bin_kernel(
    const int* __restrict__ src, const int* __restrict__ dst,
    const float* __restrict__ ea, int* __restrict__ bcnt,
    int2* __restrict__ barr, int CAP, int E, int B) {
    __shared__ int hist[64];
    __shared__ int bbase[64];
    __shared__ int gbase[64];
    __shared__ int2 sorted[2048];
    __shared__ unsigned char bof[2048];
    const int tileBase = blockIdx.x * 2048;
    int n = E - tileBase; if (n > 2048) n = 2048; if (n <= 0) return;
    const int tid = threadIdx.x;
    if (tid < 64) hist[tid] = 0;
    __syncthreads();

    int2 ent[8]; int bk[8]; int rk[8];
#pragma unroll
    for (int k = 0; k < 8; k++) {
        int i = k * 256 + tid;
        bk[k] = -1;
        if (i < n) {
            int e = tileBase + i;
            int s = src[e], d = dst[e];
            float2 a = reinterpret_cast<const float2*>(ea)[e];
            int b = d >> BSHIFT;
            int dloc = d & (BNODES - 1);
            ent[k].x = s | (dloc << 17);
            ent[k].y = (int)((uint)f2bf(a.x) | ((uint)f2bf(a.y) << 16));
            bk[k] = b;
            rk[k] = atomicAdd(&hist[b], 1);
        }
    }
    __syncthreads();
    if (tid == 0) {
        int run = 0;
        for (int b = 0; b < B; b++) { bbase[b] = run; run += hist[b]; }
    }
    __syncthreads();
    if (tid < B && hist[tid] > 0) gbase[tid] = atomicAdd(&bcnt[tid], hist[tid]);
    __syncthreads();
#pragma unroll
    for (int k = 0; k < 8; k++) {
        if (bk[k] >= 0) {
            int p = bbase[bk[k]] + rk[k];
            sorted[p] = ent[k];
            bof[p] = (unsigned char)bk[k];
        }
    }
    __syncthreads();
    for (int i = tid; i < n; i += 256) {
        int b = bof[i];
        barr[(long)b * CAP + gbase[b] + (i - bbase[b])] = sorted[i];
    }
}

// ---------------- per-bucket exact CSR (one block per bucket) ----------------

__global__ __launch_bounds__(1024) void bucket_csr(
    const int2* __restrict__ barr, const int* __restrict__ bcnt,
    int CAP, int N, int B,
    int2* __restrict__ csr, int* __restrict__ ptr) {
    __shared__ int hist[BNODES];
    __shared__ int pairs[1024];
    __shared__ int lptr[BNODES];
    const int g = blockIdx.x;
    const int tid = threadIdx.x;
    const int cnt = bcnt[g];
    int base = 0;
    for (int b = 0; b < g; b++) base += bcnt[b];

    hist[tid] = 0; hist[tid + 1024] = 0;
    __syncthreads();
    const int2* my = barr + (long)g * CAP;
    for (int i = tid; i < cnt; i += 1024) {
        int dloc = ((uint)my[i].x) >> 17;
        atomicAdd(&hist[dloc], 1);
    }
    __syncthreads();
    int ps = hist[2 * tid] + hist[2 * tid + 1];
    pairs[tid] = ps;
    __syncthreads();
    for (int off = 1; off < 1024; off <<= 1) {
        int t = (tid >= off) ? pairs[tid - off] : 0;
        __syncthreads();
        pairs[tid] += t;
        __syncthreads();
    }
    int excl = pairs[tid] - ps;
    lptr[2 * tid] = excl;
    lptr[2 * tid + 1] = excl + hist[2 * tid];
    __syncthreads();
    for (int i = tid; i < BNODES; i += 1024) {
        long gnode = (long)g * BNODES + i;
        if (gnode <= (long)N) ptr[gnode] = base + lptr[i];
    }
    __syncthreads();
    for (int i = tid; i < cnt; i += 1024) {
        int2 v = my[i];
        int dloc = ((uint)v.x) >> 17;
        int pos = base + atomicAdd(&lptr[dloc], 1);
        int2 o; o.x = v.x & 0x1FFFF; o.y = v.y;
        csr[pos] = o;
    }
}

// ---------------- CSR gather (one wave per node, 32-bit saddr addressing) ----------------

__global__ __launch_bounds__(256) void gather_kernel(
    const uint* __restrict__ Au, const int* __restrict__ ptr,
    const int2* __restrict__ csr, const float* __restrict__ we,
    uint* __restrict__ B, int N) {
    int node = blockIdx.x * 4 + (threadIdx.x >> 6);
    if (node >= N) return;
    int t = threadIdx.x & 63;
    int c = 2 * t;
    float w0x = we[c], w0y = we[c + 1];
    float w1x = we[128 + c], w1y = we[128 + c + 1];

    const char* Ab = (const char*)Au;
    const uint t4 = (uint)t * 4u;
#define LD(sidx) (*(const uint*)(Ab + ((((uint)(sidx)) << 8) + t4)))
#define ACC(rv, ev)                                                      \
    {                                                                    \
        float a0 = __uint_as_float(((uint)(ev)) << 16);                  \
        float a1 = __uint_as_float(((uint)(ev)) & 0xffff0000u);          \
        float vx = __uint_as_float((rv) << 16);                          \
        float vy = __uint_as_float((rv) & 0xffff0000u);                  \
        vx = fmaf(a0, w0x, fmaf(a1, w1x, vx));                           \
        vy = fmaf(a0, w0y, fmaf(a1, w1y, vy));                           \
        ax += fmaxf(vx, 0.f);                                            \
        ay += fmaxf(vy, 0.f);                                            \
    }
    uint selfv = LD(node);
    float ax = fmaxf(__uint_as_float(selfv << 16) + w0x + w1x, 0.f);
    float ay = fmaxf(__uint_as_float(selfv & 0xffff0000u) + w0y + w1y, 0.f);

    int k = ptr[node], end = ptr[node + 1];
    for (; k + 8 <= end; k += 8) {
        int2 c0 = csr[k], c1 = csr[k + 1], c2 = csr[k + 2], c3 = csr[k + 3];
        int2 c4 = csr[k + 4], c5 = csr[k + 5], c6 = csr[k + 6], c7 = csr[k + 7];
        uint r0 = LD(c0.x); uint r1 = LD(c1.x); uint r2 = LD(c2.x); uint r3 = LD(c3.x);
        uint r4 = LD(c4.x); uint r5 = LD(c5.x); uint r6 = LD(c6.x); uint r7 = LD(c7.x);
        ACC(r0, c0.y) ACC(r1, c1.y) ACC(r2, c2.y) ACC(r3, c3.y)
        ACC(r4, c4.y) ACC(r5, c5.y) ACC(r6, c6.y) ACC(r7, c7.y)
    }
    for (; k + 4 <= end; k += 4) {
        int2 c0 = csr[k], c1 = csr[k + 1], c2 = csr[k + 2], c3 = csr[k + 3];
        uint r0 = LD(c0.x); uint r1 = LD(c1.x); uint r2 = LD(c2.x); uint r3 = LD(c3.x);
        ACC(r0, c0.y) ACC(r1, c1.y) ACC(r2, c2.y) ACC(r3, c3.y)
    }
    for (; k < end; k++) {
        int2 c0 = csr[k];
        uint r0 = LD(c0.x);
        ACC(r0, c0.y)
    }
#undef ACC
#undef LD
    B[(long)node * 64 + t] = (uint)f2bf(ax) | ((uint)f2bf(ay) << 16);
}

// ---------------- MFMA GEMM: C[N][128] = A[N][K] @ W[K][128] + bias ----------------

template <int K, bool IN_F32, bool OUT_BF16, bool USE_CNT, bool RELU>
__global__ __launch_bounds__(256) void gemm_mfma(
    const void* __restrict__ Ain, const unsigned short* __restrict__ Wt,
    const float* __restrict__ bias, const int* __restrict__ ptr,
    void* __restrict__ Cout, int N) {
    constexpr int KS = K / 32;
    const int wave = threadIdx.x >> 6;
    const int lane = threadIdx.x & 63;
    const int m = lane & 15, quad = lane >> 4;
    const long rowBase = (long)blockIdx.x * 64;

    bf16x8 bfrag[2][KS];
#pragma unroll
    for (int ct = 0; ct < 2; ct++) {
        int col = (wave * 2 + ct) * 16 + m;
#pragma unroll
        for (int ks = 0; ks < KS; ks++)
            bfrag[ct][ks] = *(const bf16x8*)(Wt + (long)col * K + ks * 32 + quad * 8);
    }

#pragma unroll
    for (int rt = 0; rt < 4; rt++) {
        long row = rowBase + rt * 16 + m;
        long rc = row < N ? row : (long)N - 1;
        bf16x8 afrag[KS];
        if (IN_F32) {
            const float* arow = (const float*)Ain + rc * K;
#pragma unroll
            for (int ks = 0; ks < KS; ks++) {
                float4 lo = *(const float4*)(arow + ks * 32 + quad * 8);
                float4 hi = *(const float4*)(arow + ks * 32 + quad * 8 + 4);
                bf16x8 f;
                f[0] = (short)f2bf(lo.x); f[1] = (short)f2bf(lo.y);
                f[2] = (short)f2bf(lo.z); f[3] = (short)f2bf(lo.w);
                f[4] = (short)f2bf(hi.x); f[5] = (short)f2bf(hi.y);
                f[6] = (short)f2bf(hi.z); f[7] = (short)f2bf(hi.w);
                afrag[ks] = f;
            }
        } else {
            const unsigned short* arow = (const unsigned short*)Ain + rc * K;
#pragma unroll
            for (int ks = 0; ks < KS; ks++)
                afrag[ks] = *(const bf16x8*)(arow + ks * 32 + quad * 8);
        }

#pragma unroll
        for (int ct = 0; ct < 2; ct++) {
            f32x4 acc = {0.f, 0.f, 0.f, 0.f};
#pragma unroll
            for (int ks = 0; ks < KS; ks++)
                acc = __builtin_amdgcn_mfma_f32_16x16x32_bf16(afrag[ks], bfrag[ct][ks], acc, 0, 0, 0);

            int col = (wave * 2 + ct) * 16 + m;
            float b = bias[col];
#pragma unroll
            for (int r = 0; r < 4; r++) {
                long orow = rowBase + rt * 16 + quad * 4 + r;
                if (orow < N) {
                    float v = acc[r];
                    if (USE_CNT) v += b * (float)(ptr[orow + 1] - ptr[orow] + 1);
                    else v += b;
                    if (RELU) v = fmaxf(v, 0.f);
                    if (OUT_BF16) ((unsigned short*)Cout)[orow * 128 + col] = f2bf(v);
                    else ((float*)Cout)[orow * 128 + col] = v;
                }
            }
        }
    }
}

// ---------------- fused middle GEMMs: A2 = (relu(B@W12 + cnt*b12)) @ W21 + b21 ----------------
// B fragments straight from global; intermediate through LDS (layout C->A).

__global__ __launch_bounds__(256) void fused_mid_gemm(
    const unsigned short* __restrict__ Bin, const int* __restrict__ ptr,
    const unsigned short* __restrict__ WtA, const float* __restrict__ biasA,
    const unsigned short* __restrict__ WtB, const float* __restrict__ biasB,
    unsigned short* __restrict__ Cout, int N) {
    __shared__ unsigned short ts[64 * 136];
    const int wave = threadIdx.x >> 6;
    const int lane = threadIdx.x & 63;
    const int m = lane & 15, quad = lane >> 4;
    const long rowBase = (long)blockIdx.x * 64;

    bf16x8 bfrag[2][4];
#pragma unroll
    for (int ct = 0; ct < 2; ct++) {
        int col = (wave * 2 + ct) * 16 + m;
#pragma unroll
        for (int ks = 0; ks < 4; ks++)
            bfrag[ct][ks] = *(const bf16x8*)(WtA + (long)col * 128 + ks * 32 + quad * 8);
    }

    // phase A: B @ W12 -> acc
    f32x4 acc[4][2];
#pragma unroll
    for (int rt = 0; rt < 4; rt++) {
        long row = rowBase + rt * 16 + m;
        long rc = row < N ? row : (long)N - 1;
        const unsigned short* arow = Bin + rc * 128;
        bf16x8 af[4];
#pragma unroll
        for (int ks = 0; ks < 4; ks++)
            af[ks] = *(const bf16x8*)(arow + ks * 32 + quad * 8);
#pragma unroll
        for (int ct = 0; ct < 2; ct++) {
            f32x4 a = {0.f, 0.f, 0.f, 0.f};
#pragma unroll
            for (int ks = 0; ks < 4; ks++)
                a = __builtin_amdgcn_mfma_f32_16x16x32_bf16(af[ks], bfrag[ct][ks], a, 0, 0, 0);
            acc[rt][ct] = a;
        }
    }

    // epilogue A: relu(acc + cnt*b12) -> LDS (bf16)
#pragma unroll
    for (int rt = 0; rt < 4; rt++) {
        float cntf[4];
#pragma unroll
        for (int r = 0; r < 4; r++) {
            long grow = rowBase + rt * 16 + quad * 4 + r;
            cntf[r] = (grow < N) ? (float)(ptr[grow + 1] - ptr[grow] + 1) : 1.f;
        }
#pragma unroll
        for (int ct = 0; ct < 2; ct++) {
            int col = (wave * 2 + ct) * 16 + m;
            float b = biasA[col];
#pragma unroll
            for (int r = 0; r < 4; r++) {
                int row = rt * 16 + quad * 4 + r;
                ts[row * 136 + col] = f2bf(fmaxf(acc[rt][ct][r] + b * cntf[r], 0.f));
            }
        }
    }
    __syncthreads();

    // phase B: tile @ W21 + b21 -> bf16 out
#pragma unroll
    for (int ct = 0; ct < 2; ct++) {
        int col = (wave * 2 + ct) * 16 + m;
#pragma unroll
        for (int ks = 0; ks < 4; ks++)
            bfrag[ct][ks] = *(const bf16x8*)(WtB + (long)col * 128 + ks * 32 + quad * 8);
    }
#pragma unroll
    for (int rt = 0; rt < 4; rt++) {
        const unsigned short* lr = ts + (rt * 16 + m) * 136;
        bf16x8 af[4];
#pragma unroll
        for (int ks = 0; ks < 4; ks++)
            af[ks] = *(const bf16x8*)(lr + ks * 32 + quad * 8);
#pragma unroll
        for (int ct = 0; ct < 2; ct++) {
            f32x4 a = {0.f, 0.f, 0.f, 0.f};
#pragma unroll
            for (int ks = 0; ks < 4; ks++)
                a = __builtin_amdgcn_mfma_f32_16x16x32_bf16(af[ks], bfrag[ct][ks], a, 0, 0, 0);
            int col = (wave * 2 + ct) * 16 + m;
            float b = biasB[col];
#pragma unroll
            for (int r = 0; r < 4; r++) {
                long grow = rowBase + rt * 16 + quad * 4 + r;
                if (grow < N) Cout[grow * 128 + col] = f2bf(a[r] + b);
            }
        }
    }
}

// ---------------- launch ----------------

extern "C" void kernel_launch(void* const* d_in, const int* in_sizes, int n_in,
                              void* d_out, int out_size, void* d_ws, size_t ws_size,
                              hipStream_t stream) {
    const float* x   = (const float*)d_in[0];
    const int*   ei  = (const int*)d_in[1];
    const float* ea  = (const float*)d_in[2];
    const float* W11 = (const float*)d_in[3];
    const float* b11 = (const float*)d_in[4];
    const float* W12 = (const float*)d_in[5];
    const float* b12 = (const float*)d_in[6];
    const float* W21 = (const float*)d_in[7];
    const float* b21 = (const float*)d_in[8];
    const float* W22 = (const float*)d_in[9];
    const float* b22 = (const float*)d_in[10];
    float* out = (float*)d_out;

    const int N = in_sizes[0] / 64;
    const int E = in_sizes[1] / 2;
    const int* src = ei;
    const int* dst = ei + E;

    const int B = (N + BNODES - 1) >> BSHIFT;
    const int CAP = E / B + 4096;

    char* p = (char*)d_ws;
    unsigned short* A_bf = (unsigned short*)p;  p += (size_t)N * 128 * 2;  // 25.6 MB
    unsigned short* B_bf = (unsigned short*)p;
    int2* barr = (int2*)B_bf;                   p += (size_t)N * 128 * 2;  // 25.6 MB (aliased)
    int2* csr  = (int2*)p;                      p += (size_t)E * 8;        // 12.8 MB
    int* ptr   = (int*)p;                       p += (size_t)(N + 1) * 4;
    int* bcnt  = (int*)p;                       p += 64 * 4;
    unsigned short* Wt11 = (unsigned short*)p;  p += (size_t)64 * 128 * 2;
    unsigned short* Wt12 = (unsigned short*)p;  p += (size_t)128 * 128 * 2;
    unsigned short* Wt21 = (unsigned short*)p;  p += (size_t)128 * 128 * 2;
    unsigned short* Wt22 = (unsigned short*)p;

    const int binBlocks = (E + 2047) / 2048;
    const int gatherBlocks = (N + 3) / 4;
    const int tileBlocks = (N + 63) / 64;

    init_kernel<<<1, 64, 0, stream>>>(bcnt, ptr, N, E);
    wprep_all<<<(448 * 128 + 255) / 256, 256, 0, stream>>>(W11, W12, W21, W22,
                                                           Wt11, Wt12, Wt21, Wt22);

    bin_kernel<<<binBlocks, 256, 0, stream>>>(src, dst, ea, bcnt, barr, CAP, E, B);
    bucket_csr<<<B, 1024, 0, stream>>>(barr, bcnt, CAP, N, B, csr, ptr);

    // layer 1: x @ W11 -> A (bf16)
    gemm_mfma<64, true, true, false, false><<<tileBlocks, 256, 0, stream>>>(
        x, Wt11, b11, nullptr, A_bf, N);
    gather_kernel<<<gatherBlocks, 256, 0, stream>>>((const uint*)A_bf, ptr, csr,
                                                    W11 + 64 * 128, (uint*)B_bf, N);
    // fused middle: relu(B@W12 + cnt*b12) @ W21 + b21 -> A (layer2 input)
    fused_mid_gemm<<<tileBlocks, 256, 0, stream>>>(B_bf, ptr, Wt12, b12, Wt21, b21, A_bf, N);
    gather_kernel<<<gatherBlocks, 256, 0, stream>>>((const uint*)A_bf, ptr, csr,
                                                    W21 + 128 * 128, (uint*)B_bf, N);
    // last: B2 @ W22 + cnt*b22 -> out (fp32)
    gemm_mfma<128, false, false, true, false><<<tileBlocks, 256, 0, stream>>>(
        B_bf, Wt22, b22, ptr, out, N);
}

// Round 7
// 369.988 us; speedup vs baseline: 1.5152x; 1.0846x over previous
//
#include <hip/hip_runtime.h>

// GIN (2x GINE conv): bucketed CSR build + scalarized CSR gather + bf16 MFMA
// GEMMs (middle two fused through LDS).
// Pipeline:  A  = x @ W11 + b11                       (gemm_mfma, f32->bf16)
//            B  = gather(A)                           (gather_kernel)
//            A2 = relu(B@W12 + cnt*b12) @ W21 + b21   (fused_mid, bf16)
//            B2 = gather(A2)                          (gather_kernel)
//            out= B2 @ W22 + cnt*b22                  (gemm_mfma, f32 out)
// gather: one wave per node; csr entries / ea-unpack / loop bounds are
// wave-uniform -> forced to SALU+SMEM via readfirstlane; VALU does only the
// per-lane relu-accumulate; VMEM does only the 256B row gathers.

typedef unsigned int uint;
typedef __attribute__((ext_vector_type(8))) short bf16x8;
typedef __attribute__((ext_vector_type(4))) float f32x4;

#define BSHIFT 10            // 1024 nodes per bucket -> 98 buckets
#define BNODES (1 << BSHIFT)

static __device__ __forceinline__ unsigned short f2bf(float f) {
    uint u = __float_as_uint(f);
    uint r = (u + 0x7fffu + ((u >> 16) & 1u)) >> 16;
    return (unsigned short)r;
}

// ---------------- weight prep (+init): W[K][128] fp32 -> Wt[128][K] bf16 ----------------

__global__ void wprep_all(const float* __restrict__ W11, const float* __restrict__ W12,
                          const float* __restrict__ W21, const float* __restrict__ W22,
                          unsigned short* Wt11, unsigned short* Wt12,
                          unsigned short* Wt21, unsigned short* Wt22,
                          int* bcnt, int* ptr, int N, int E) {
    int idx = blockIdx.x * 256 + threadIdx.x;
    if (idx < 128) bcnt[idx] = 0;
    if (idx == 128) ptr[N] = E;
    const float* W; unsigned short* Wt; int K; int off;
    if (idx < 64 * 128)        { W = W11; Wt = Wt11; K = 64;  off = idx; }
    else if (idx < 192 * 128)  { W = W12; Wt = Wt12; K = 128; off = idx - 64 * 128; }
    else if (idx < 320 * 128)  { W = W21; Wt = Wt21; K = 128; off = idx - 192 * 128; }
    else if (idx < 448 * 128)  { W = W22; Wt = Wt22; K = 128; off = idx - 320 * 128; }
    else return;
    int k = off >> 7, n = off & 127;
    Wt[n * K + k] = f2bf(W[k * 128 + n]);
}

// ---------------- binning: 4096-edge tile sort in LDS, coalesced chunk appends ----------------
// entry.x = src | (dloc << 17)  (src < 2^17, dloc < 2^10), entry.y = ea bf16x2

__global__ __launch_bounds__(512) void bin_kernel(
    const int* __restrict__ src, const int* __restrict__ dst,
    const float* __restrict__ ea, int* __restrict__ bcnt,
    int2* __restrict__ barr, int CAP, int E, int B) {
    __shared__ int hist[128];
    __shared__ int bbase[128];
    __shared__ int gbase[128];
    __shared__ int2 sorted[4096];
    __shared__ unsigned char bof[4096];
    const int tileBase = blockIdx.x * 4096;
    int n = E - tileBase; if (n > 4096) n = 4096; if (n <= 0) return;
    const int tid = threadIdx.x;
    if (tid < 128) hist[tid] = 0;
    __syncthreads();

    int2 ent[8]; int bk[8]; int rk[8];
#pragma unroll
    for (int k = 0; k < 8; k++) {
        int i = k * 512 + tid;
        bk[k] = -1;
        if (i < n) {
            int e = tileBase + i;
            int s = src[e], d = dst[e];
            float2 a = reinterpret_cast<const float2*>(ea)[e];
            int b = d >> BSHIFT;
            int dloc = d & (BNODES - 1);
            ent[k].x = s | (dloc << 17);
            ent[k].y = (int)((uint)f2bf(a.x) | ((uint)f2bf(a.y) << 16));
            bk[k] = b;
            rk[k] = atomicAdd(&hist[b], 1);
        }
    }
    __syncthreads();
    if (tid == 0) {
        int run = 0;
        for (int b = 0; b < B; b++) { bbase[b] = run; run += hist[b]; }
    }
    __syncthreads();
    if (tid < B && hist[tid] > 0) gbase[tid] = atomicAdd(&bcnt[tid], hist[tid]);
    __syncthreads();
#pragma unroll
    for (int k = 0; k < 8; k++) {
        if (bk[k] >= 0) {
            int p = bbase[bk[k]] + rk[k];
            sorted[p] = ent[k];
            bof[p] = (unsigned char)bk[k];
        }
    }
    __syncthreads();
    for (int i = tid; i < n; i += 512) {
        int b = bof[i];
        barr[(long)b * CAP + gbase[b] + (i - bbase[b])] = sorted[i];
    }
}

// ---------------- per-bucket exact CSR (one block per 1024-node bucket) ----------------

__global__ __launch_bounds__(1024) void bucket_csr(
    const int2* __restrict__ barr, const int* __restrict__ bcnt,
    int CAP, int N, int B,
    int2* __restrict__ csr, int* __restrict__ ptr) {
    __shared__ int hist[BNODES];
    __shared__ int scn[BNODES];
    __shared__ int lptr[BNODES];
    const int g = blockIdx.x;
    const int tid = threadIdx.x;
    const int cnt = bcnt[g];
    int base = 0;
    for (int b = 0; b < g; b++) base += bcnt[b];

    hist[tid] = 0;
    __syncthreads();
    const int2* my = barr + (long)g * CAP;
    for (int i = tid; i < cnt; i += 1024) {
        int dloc = ((uint)my[i].x) >> 17;
        atomicAdd(&hist[dloc], 1);
    }
    __syncthreads();
    int v = hist[tid];
    scn[tid] = v;
    __syncthreads();
    for (int off = 1; off < 1024; off <<= 1) {
        int t = (tid >= off) ? scn[tid - off] : 0;
        __syncthreads();
        scn[tid] += t;
        __syncthreads();
    }
    int excl = scn[tid] - v;
    lptr[tid] = excl;
    long gnode = (long)g * BNODES + tid;
    if (gnode < (long)N) ptr[gnode] = base + excl;
    __syncthreads();
    for (int i = tid; i < cnt; i += 1024) {
        int2 e = my[i];
        int dloc = ((uint)e.x) >> 17;
        int pos = base + atomicAdd(&lptr[dloc], 1);
        int2 o; o.x = e.x & 0x1FFFF; o.y = e.y;
        csr[pos] = o;
    }
}

// ---------------- CSR gather: wave/node, scalarized edge stream ----------------

__global__ __launch_bounds__(256) void gather_kernel(
    const uint* __restrict__ Au, const int* __restrict__ ptr,
    const int2* __restrict__ csr, const float* __restrict__ we,
    uint* __restrict__ B, int N) {
    int node = blockIdx.x * 4 + (threadIdx.x >> 6);
    if (node >= N) return;
    int t = threadIdx.x & 63;
    int c = 2 * t;
    float w0x = we[c], w0y = we[c + 1];
    float w1x = we[128 + c], w1y = we[128 + c + 1];

    const char* Ab = (const char*)Au;
    const uint t4 = (uint)t * 4u;
#define LD(sidx) (*(const uint*)(Ab + ((((uint)(sidx)) << 8) + t4)))
#define ACC(rv, ev)                                                      \
    {                                                                    \
        float a0 = __uint_as_float(((uint)(ev)) << 16);                  \
        float a1 = __uint_as_float(((uint)(ev)) & 0xffff0000u);          \
        float vx = __uint_as_float((rv) << 16);                          \
        float vy = __uint_as_float((rv) & 0xffff0000u);                  \
        vx = fmaf(a0, w0x, fmaf(a1, w1x, vx));                           \
        vy = fmaf(a0, w0y, fmaf(a1, w1y, vy));                           \
        ax += fmaxf(vx, 0.f);                                            \
        ay += fmaxf(vy, 0.f);                                            \
    }
    uint selfv = LD(node);
    float ax = fmaxf(__uint_as_float(selfv << 16) + w0x + w1x, 0.f);
    float ay = fmaxf(__uint_as_float(selfv & 0xffff0000u) + w0y + w1y, 0.f);

    // wave-uniform edge range -> scalar loop control + scalar csr loads
    int k   = __builtin_amdgcn_readfirstlane(ptr[node]);
    int end = __builtin_amdgcn_readfirstlane(ptr[node + 1]);

    for (; k + 8 <= end; k += 8) {
        int2 c0 = csr[k],     c1 = csr[k + 1], c2 = csr[k + 2], c3 = csr[k + 3];
        int2 c4 = csr[k + 4], c5 = csr[k + 5], c6 = csr[k + 6], c7 = csr[k + 7];
        uint r0 = LD(c0.x); uint r1 = LD(c1.x); uint r2 = LD(c2.x); uint r3 = LD(c3.x);
        uint r4 = LD(c4.x); uint r5 = LD(c5.x); uint r6 = LD(c6.x); uint r7 = LD(c7.x);
        ACC(r0, c0.y) ACC(r1, c1.y) ACC(r2, c2.y) ACC(r3, c3.y)
        ACC(r4, c4.y) ACC(r5, c5.y) ACC(r6, c6.y) ACC(r7, c7.y)
    }
    for (; k + 2 <= end; k += 2) {
        int2 c0 = csr[k], c1 = csr[k + 1];
        uint r0 = LD(c0.x); uint r1 = LD(c1.x);
        ACC(r0, c0.y) ACC(r1, c1.y)
    }
    if (k < end) {
        int2 c0 = csr[k];
        uint r0 = LD(c0.x);
        ACC(r0, c0.y)
    }
#undef ACC
#undef LD
    B[(long)node * 64 + t] = (uint)f2bf(ax) | ((uint)f2bf(ay) << 16);
}

// ---------------- MFMA GEMM: C[N][128] = A[N][K] @ W[K][128] + bias ----------------

template <int K, bool IN_F32, bool OUT_BF16, bool USE_CNT, bool RELU>
__global__ __launch_bounds__(256) void gemm_mfma(
    const void* __restrict__ Ain, const unsigned short* __restrict__ Wt,
    const float* __restrict__ bias, const int* __restrict__ ptr,
    void* __restrict__ Cout, int N) {
    constexpr int KS = K / 32;
    const int wave = threadIdx.x >> 6;
    const int lane = threadIdx.x & 63;
    const int m = lane & 15, quad = lane >> 4;
    const long rowBase = (long)blockIdx.x * 64;

    bf16x8 bfrag[2][KS];
#pragma unroll
    for (int ct = 0; ct < 2; ct++) {
        int col = (wave * 2 + ct) * 16 + m;
#pragma unroll
        for (int ks = 0; ks < KS; ks++)
            bfrag[ct][ks] = *(const bf16x8*)(Wt + (long)col * K + ks * 32 + quad * 8);
    }

#pragma unroll
    for (int rt = 0; rt < 4; rt++) {
        long row = rowBase + rt * 16 + m;
        long rc = row < N ? row : (long)N - 1;
        bf16x8 afrag[KS];
        if (IN_F32) {
            const float* arow = (const float*)Ain + rc * K;
#pragma unroll
            for (int ks = 0; ks < KS; ks++) {
                float4 lo = *(const float4*)(arow + ks * 32 + quad * 8);
                float4 hi = *(const float4*)(arow + ks * 32 + quad * 8 + 4);
                bf16x8 f;
                f[0] = (short)f2bf(lo.x); f[1] = (short)f2bf(lo.y);
                f[2] = (short)f2bf(lo.z); f[3] = (short)f2bf(lo.w);
                f[4] = (short)f2bf(hi.x); f[5] = (short)f2bf(hi.y);
                f[6] = (short)f2bf(hi.z); f[7] = (short)f2bf(hi.w);
                afrag[ks] = f;
            }
        } else {
            const unsigned short* arow = (const unsigned short*)Ain + rc * K;
#pragma unroll
            for (int ks = 0; ks < KS; ks++)
                afrag[ks] = *(const bf16x8*)(arow + ks * 32 + quad * 8);
        }

#pragma unroll
        for (int ct = 0; ct < 2; ct++) {
            f32x4 acc = {0.f, 0.f, 0.f, 0.f};
#pragma unroll
            for (int ks = 0; ks < KS; ks++)
                acc = __builtin_amdgcn_mfma_f32_16x16x32_bf16(afrag[ks], bfrag[ct][ks], acc, 0, 0, 0);

            int col = (wave * 2 + ct) * 16 + m;
            float b = bias[col];
#pragma unroll
            for (int r = 0; r < 4; r++) {
                long orow = rowBase + rt * 16 + quad * 4 + r;
                if (orow < N) {
                    float v = acc[r];
                    if (USE_CNT) v += b * (float)(ptr[orow + 1] - ptr[orow] + 1);
                    else v += b;
                    if (RELU) v = fmaxf(v, 0.f);
                    if (OUT_BF16) ((unsigned short*)Cout)[orow * 128 + col] = f2bf(v);
                    else ((float*)Cout)[orow * 128 + col] = v;
                }
            }
        }
    }
}

// ---------------- fused middle GEMMs: A2 = (relu(B@W12 + cnt*b12)) @ W21 + b21 ----------------

__global__ __launch_bounds__(256) void fused_mid_gemm(
    const unsigned short* __restrict__ Bin, const int* __restrict__ ptr,
    const unsigned short* __restrict__ WtA, const float* __restrict__ biasA,
    const unsigned short* __restrict__ WtB, const float* __restrict__ biasB,
    unsigned short* __restrict__ Cout, int N) {
    __shared__ unsigned short ts[64 * 136];
    const int wave = threadIdx.x >> 6;
    const int lane = threadIdx.x & 63;
    const int m = lane & 15, quad = lane >> 4;
    const long rowBase = (long)blockIdx.x * 64;

    bf16x8 bfrag[2][4];
#pragma unroll
    for (int ct = 0; ct < 2; ct++) {
        int col = (wave * 2 + ct) * 16 + m;
#pragma unroll
        for (int ks = 0; ks < 4; ks++)
            bfrag[ct][ks] = *(const bf16x8*)(WtA + (long)col * 128 + ks * 32 + quad * 8);
    }

    f32x4 acc[4][2];
#pragma unroll
    for (int rt = 0; rt < 4; rt++) {
        long row = rowBase + rt * 16 + m;
        long rc = row < N ? row : (long)N - 1;
        const unsigned short* arow = Bin + rc * 128;
        bf16x8 af[4];
#pragma unroll
        for (int ks = 0; ks < 4; ks++)
            af[ks] = *(const bf16x8*)(arow + ks * 32 + quad * 8);
#pragma unroll
        for (int ct = 0; ct < 2; ct++) {
            f32x4 a = {0.f, 0.f, 0.f, 0.f};
#pragma unroll
            for (int ks = 0; ks < 4; ks++)
                a = __builtin_amdgcn_mfma_f32_16x16x32_bf16(af[ks], bfrag[ct][ks], a, 0, 0, 0);
            acc[rt][ct] = a;
        }
    }

#pragma unroll
    for (int rt = 0; rt < 4; rt++) {
        float cntf[4];
#pragma unroll
        for (int r = 0; r < 4; r++) {
            long grow = rowBase + rt * 16 + quad * 4 + r;
            cntf[r] = (grow < N) ? (float)(ptr[grow + 1] - ptr[grow] + 1) : 1.f;
        }
#pragma unroll
        for (int ct = 0; ct < 2; ct++) {
            int col = (wave * 2 + ct) * 16 + m;
            float b = biasA[col];
#pragma unroll
            for (int r = 0; r < 4; r++) {
                int row = rt * 16 + quad * 4 + r;
                ts[row * 136 + col] = f2bf(fmaxf(acc[rt][ct][r] + b * cntf[r], 0.f));
            }
        }
    }
    __syncthreads();

#pragma unroll
    for (int ct = 0; ct < 2; ct++) {
        int col = (wave * 2 + ct) * 16 + m;
#pragma unroll
        for (int ks = 0; ks < 4; ks++)
            bfrag[ct][ks] = *(const bf16x8*)(WtB + (long)col * 128 + ks * 32 + quad * 8);
    }
#pragma unroll
    for (int rt = 0; rt < 4; rt++) {
        const unsigned short* lr = ts + (rt * 16 + m) * 136;
        bf16x8 af[4];
#pragma unroll
        for (int ks = 0; ks < 4; ks++)
            af[ks] = *(const bf16x8*)(lr + ks * 32 + quad * 8);
#pragma unroll
        for (int ct = 0; ct < 2; ct++) {
            f32x4 a = {0.f, 0.f, 0.f, 0.f};
#pragma unroll
            for (int ks = 0; ks < 4; ks++)
                a = __builtin_amdgcn_mfma_f32_16x16x32_bf16(af[ks], bfrag[ct][ks], a, 0, 0, 0);
            int col = (wave * 2 + ct) * 16 + m;
            float b = biasB[col];
#pragma unroll
            for (int r = 0; r < 4; r++) {
                long grow = rowBase + rt * 16 + quad * 4 + r;
                if (grow < N) Cout[grow * 128 + col] = f2bf(a[r] + b);
            }
        }
    }
}

// ---------------- launch ----------------

extern "C" void kernel_launch(void* const* d_in, const int* in_sizes, int n_in,
                              void* d_out, int out_size, void* d_ws, size_t ws_size,
                              hipStream_t stream) {
    const float* x   = (const float*)d_in[0];
    const int*   ei  = (const int*)d_in[1];
    const float* ea  = (const float*)d_in[2];
    const float* W11 = (const float*)d_in[3];
    const float* b11 = (const float*)d_in[4];
    const float* W12 = (const float*)d_in[5];
    const float* b12 = (const float*)d_in[6];
    const float* W21 = (const float*)d_in[7];
    const float* b21 = (const float*)d_in[8];
    const float* W22 = (const float*)d_in[9];
    const float* b22 = (const float*)d_in[10];
    float* out = (float*)d_out;

    const int N = in_sizes[0] / 64;
    const int E = in_sizes[1] / 2;
    const int* src = ei;
    const int* dst = ei + E;

    const int B = (N + BNODES - 1) >> BSHIFT;     // 98 buckets
    const int CAP = E / B + 4096;                 // per-bucket capacity

    char* p = (char*)d_ws;
    unsigned short* A_bf = (unsigned short*)p;  p += (size_t)N * 128 * 2;  // 25.6 MB
    unsigned short* B_bf = (unsigned short*)p;
    int2* barr = (int2*)B_bf;                   p += (size_t)N * 128 * 2;  // 25.6 MB (aliased, barr ~16 MB)
    int2* csr  = (int2*)p;                      p += (size_t)E * 8;        // 12.8 MB
    int* ptr   = (int*)p;                       p += (size_t)(N + 1) * 4;
    int* bcnt  = (int*)p;                       p += 128 * 4;
    unsigned short* Wt11 = (unsigned short*)p;  p += (size_t)64 * 128 * 2;
    unsigned short* Wt12 = (unsigned short*)p;  p += (size_t)128 * 128 * 2;
    unsigned short* Wt21 = (unsigned short*)p;  p += (size_t)128 * 128 * 2;
    unsigned short* Wt22 = (unsigned short*)p;

    const int binBlocks = (E + 4095) / 4096;
    const int gatherBlocks = (N + 3) / 4;
    const int tileBlocks = (N + 63) / 64;

    wprep_all<<<(448 * 128 + 255) / 256, 256, 0, stream>>>(W11, W12, W21, W22,
                                                           Wt11, Wt12, Wt21, Wt22,
                                                           bcnt, ptr, N, E);
    bin_kernel<<<binBlocks, 512, 0, stream>>>(src, dst, ea, bcnt, barr, CAP, E, B);
    bucket_csr<<<B, 1024, 0, stream>>>(barr, bcnt, CAP, N, B, csr, ptr);

    // layer 1: x @ W11 -> A (bf16)
    gemm_mfma<64, true, true, false, false><<<tileBlocks, 256, 0, stream>>>(
        x, Wt11, b11, nullptr, A_bf, N);
    gather_kernel<<<gatherBlocks, 256, 0, stream>>>((const uint*)A_bf, ptr, csr,
                                                    W11 + 64 * 128, (uint*)B_bf, N);
    // fused middle: relu(B@W12 + cnt*b12) @ W21 + b21 -> A (layer2 input)
    fused_mid_gemm<<<tileBlocks, 256, 0, stream>>>(B_bf, ptr, Wt12, b12, Wt21, b21, A_bf, N);
    gather_kernel<<<gatherBlocks, 256, 0, stream>>>((const uint*)A_bf, ptr, csr,
                                                    W21 + 128 * 128, (uint*)B_bf, N);
    // last: B2 @ W22 + cnt*b22 -> out (fp32)
    gemm_mfma<128, false, false, true, false><<<tileBlocks, 256, 0, stream>>>(
        B_bf, Wt22, b22, ptr, out, N);
}